// Round 2
// baseline (869.842 us; speedup 1.0000x reference)
//
#include <hip/hip_runtime.h>

// PolicyHead fused kernel, R2.
// R1 post-mortem: prep_weights bit-field decode overlapped (n took 7 bits),
// reading 2MB OOB past w1/w2/w3 -> GPU memory fault. Fixed: j|lane|t|n =
// bits 0-2|3-8|9-11|12-15. Also: don't trust ws_size — fall back to inline
// fp32->bf16 fragment conversion if the workspace can't hold 384 KB.
//
// Strategy: one block per 64-row batch, 4 waves, wave w owns rows 16w..16w+15.
// bf16 MFMA 16x16x32 for all GEMMs; C/D layout col=lane&15,row=quad*4+reg.

typedef __bf16 bf16_t;
typedef __bf16 bf16x8 __attribute__((ext_vector_type(8)));
typedef float  f32x4  __attribute__((ext_vector_type(4)));

#define PSCALE 0.0625f
#define NPOL   1858
#define KROW   264   // ks row stride in bf16 elems (+8 pad -> 2-way LDS only)

__global__ void prep_weights(const float* __restrict__ w1,
                             const float* __restrict__ w2,
                             const float* __restrict__ w3,
                             bf16_t* __restrict__ wf) {
    // wf flat layout: [which][n(16)][t(8)][lane(64)][j(8)]
    int i = blockIdx.x * 256 + threadIdx.x;      // 0 .. 3*65536-1
    int which = i >> 16;
    int r = i & 65535;
    int j    = r & 7;
    int lane = (r >> 3) & 63;
    int t    = (r >> 9) & 7;
    int n    = (r >> 12) & 15;
    const float* w = (which == 0) ? w1 : (which == 1 ? w2 : w3);
    int row = n * 16 + (lane & 15);              // output-col index (w row)
    int col = t * 32 + (lane >> 4) * 8 + j;      // k index
    wf[i] = (bf16_t)w[row * 256 + col];
}

// B-operand fragment for col-tile n, k-tile t: lane holds
// w[n*16 + (lane&15)][t*32 + (lane>>4)*8 + j], j=0..7.
template <bool USE_WS>
__device__ __forceinline__ bf16x8 wfrag(const bf16_t* __restrict__ wl,
                                        const float* __restrict__ w,
                                        int n, int t, int lane) {
    if (USE_WS) {
        return *(const bf16x8*)(wl + (((n * 8 + t) * 64 + lane) << 3));
    } else {
        int l15 = lane & 15, quad = lane >> 4;
        const float* p = w + (n * 16 + l15) * 256 + t * 32 + quad * 8;
        f32x4 lo = *(const f32x4*)p;
        f32x4 hi = *(const f32x4*)(p + 4);
        bf16x8 v;
        v[0] = (bf16_t)lo[0]; v[1] = (bf16_t)lo[1];
        v[2] = (bf16_t)lo[2]; v[3] = (bf16_t)lo[3];
        v[4] = (bf16_t)hi[0]; v[5] = (bf16_t)hi[1];
        v[6] = (bf16_t)hi[2]; v[7] = (bf16_t)hi[3];
        return v;
    }
}

template <bool USE_WS>
__global__ __launch_bounds__(256)
void policy_main(const float* __restrict__ x,
                 const bf16_t* __restrict__ wf,   // [3][16][8][64][8] bf16
                 const float* __restrict__ w1,
                 const float* __restrict__ w2,
                 const float* __restrict__ w3,
                 const float* __restrict__ b1,
                 const float* __restrict__ b2,
                 const float* __restrict__ b3,
                 const float* __restrict__ w4,
                 const int*   __restrict__ gidx,
                 float* __restrict__ out) {
    __shared__ __align__(16) bf16_t ks[64 * KROW];        // 33792 B
    __shared__ __align__(16) bf16_t scratch[4][16 * 24];  //  3072 B (per-wave)
    __shared__ float fullbuf[67 * 64];                    // 17152 B
    __shared__ float promoLDS[4][8];                      //   128 B

    const int tid  = threadIdx.x;
    const int lane = tid & 63;
    const int wv   = tid >> 6;        // wave id 0..3
    const int quad = lane >> 4;       // 0..3
    const int l15  = lane & 15;
    const int bat  = blockIdx.x;
    const int R    = wv * 16;         // row base within batch

    // ---- x A-fragments (fp32 -> bf16). xa[t][j] = x[R+l15][t*32+quad*8+j]
    bf16x8 xa[8];
    {
        const float* xrow = x + ((size_t)bat * 64 + R + l15) * 256;
        #pragma unroll
        for (int t = 0; t < 8; ++t) {
            f32x4 lo = *(const f32x4*)(xrow + t * 32 + quad * 8);
            f32x4 hi = *(const f32x4*)(xrow + t * 32 + quad * 8 + 4);
            bf16x8 v;
            v[0] = (bf16_t)lo[0]; v[1] = (bf16_t)lo[1];
            v[2] = (bf16_t)lo[2]; v[3] = (bf16_t)lo[3];
            v[4] = (bf16_t)hi[0]; v[5] = (bf16_t)hi[1];
            v[6] = (bf16_t)hi[2]; v[7] = (bf16_t)hi[3];
            xa[t] = v;
        }
    }

    bf16x8 oa[8];   // out A-frags (layer-2/3 input)
    bf16x8 qa[8];   // q  A-frags (logits input)

    // ---------------- layer 1: out = relu(x@w1.T + b1) -> oa ----------------
    {
        const bf16_t* wl = wf;
        #pragma unroll
        for (int n = 0; n < 16; ++n) {
            f32x4 acc = {0.f, 0.f, 0.f, 0.f};
            #pragma unroll
            for (int t = 0; t < 8; ++t)
                acc = __builtin_amdgcn_mfma_f32_16x16x32_bf16(
                    xa[t], wfrag<USE_WS>(wl, w1, n, t, lane), acc, 0, 0, 0);
            float bias = b1[n * 16 + l15];
            #pragma unroll
            for (int r2 = 0; r2 < 4; ++r2) {
                float v = fmaxf(acc[r2] + bias, 0.f);
                scratch[wv][(quad * 4 + r2) * 24 + l15] = (bf16_t)v;  // C/D scatter
            }
            // read back in A-operand order (wave-local; same-wave DS is in order)
            bf16x8 half = *(bf16x8*)&scratch[wv][l15 * 24 + (quad & 1) * 8];
            if ((quad >> 1) == (n & 1)) oa[n >> 1] = half;
        }
    }

    // ---------------- layer 2: q = out@w2.T + b2 -> qa ----------------
    {
        const bf16_t* wl = wf + 65536;
        #pragma unroll
        for (int n = 0; n < 16; ++n) {
            f32x4 acc = {0.f, 0.f, 0.f, 0.f};
            #pragma unroll
            for (int t = 0; t < 8; ++t)
                acc = __builtin_amdgcn_mfma_f32_16x16x32_bf16(
                    oa[t], wfrag<USE_WS>(wl, w2, n, t, lane), acc, 0, 0, 0);
            float bias = b2[n * 16 + l15];
            #pragma unroll
            for (int r2 = 0; r2 < 4; ++r2)
                scratch[wv][(quad * 4 + r2) * 24 + l15] = (bf16_t)(acc[r2] + bias);
            bf16x8 half = *(bf16x8*)&scratch[wv][l15 * 24 + (quad & 1) * 8];
            if ((quad >> 1) == (n & 1)) qa[n >> 1] = half;
        }
    }

    // ---------------- layer 3: k = out@w3.T + b3 -> ks (LDS) ----------------
    {
        const bf16_t* wl = wf + 2 * 65536;
        #pragma unroll
        for (int n = 0; n < 16; ++n) {
            f32x4 acc = {0.f, 0.f, 0.f, 0.f};
            #pragma unroll
            for (int t = 0; t < 8; ++t)
                acc = __builtin_amdgcn_mfma_f32_16x16x32_bf16(
                    oa[t], wfrag<USE_WS>(wl, w3, n, t, lane), acc, 0, 0, 0);
            float bias = b3[n * 16 + l15];
            #pragma unroll
            for (int r2 = 0; r2 < 4; ++r2)
                ks[(R + quad * 4 + r2) * KROW + n * 16 + l15] = (bf16_t)(acc[r2] + bias);
        }
    }

    __syncthreads();   // ks complete across all waves

    // ---------------- logits = q@k.T * SCALE -> fullbuf rows 0..63 ----------
    {
        #pragma unroll
        for (int n = 0; n < 4; ++n) {
            f32x4 acc = {0.f, 0.f, 0.f, 0.f};
            #pragma unroll
            for (int t = 0; t < 8; ++t) {
                bf16x8 kfr = *(const bf16x8*)&ks[(n * 16 + l15) * KROW + t * 32 + quad * 8];
                acc = __builtin_amdgcn_mfma_f32_16x16x32_bf16(qa[t], kfr, acc, 0, 0, 0);
            }
            #pragma unroll
            for (int r2 = 0; r2 < 4; ++r2)
                fullbuf[(R + quad * 4 + r2) * 64 + n * 16 + l15] = acc[r2] * PSCALE;
        }
    }

    // ---------------- promo offsets: offs[p][s] = k[56+s]·w4[p] -------------
    {
        int s = lane >> 3, seg = lane & 7;     // wave wv handles p = wv
        float p = 0.f;
        const float* wrow = w4 + wv * 256;
        #pragma unroll 8
        for (int hh = 0; hh < 32; ++hh) {
            int h = seg * 32 + hh;
            p += (float)ks[(56 + s) * KROW + h] * wrow[h];
        }
        p += __shfl_down(p, 4);
        p += __shfl_down(p, 2);
        p += __shfl_down(p, 1);
        if (seg == 0) promoLDS[wv][s] = p;
    }
    __syncthreads();   // logits + promoLDS ready

    // ---------------- promo rows 64..66 of fullbuf --------------------------
    if (tid < 192) {
        int u = tid >> 6, v = tid & 63;
        int mm = u * 64 + v;                   // flat 0..191 over (8 x 24)
        int r_ = mm / 24, c_ = mm - r_ * 24;
        int c3 = c_ / 3, cp = c_ - c3 * 3;     // c3 = s (0..7), cp = p (0..2)
        fullbuf[(64 + u) * 64 + v] =
            promoLDS[cp][c3] + promoLDS[3][c3] +
            fullbuf[(48 + r_) * 64 + 56 + c3];
    }
    __syncthreads();

    // ---------------- gather ------------------------------------------------
    {
        float* orow = out + (size_t)bat * NPOL;
        for (int g = tid; g < NPOL; g += 256)
            orow[g] = fullbuf[gidx[g]];
    }
}

extern "C" void kernel_launch(void* const* d_in, const int* in_sizes, int n_in,
                              void* d_out, int out_size, void* d_ws, size_t ws_size,
                              hipStream_t stream) {
    const float* x    = (const float*)d_in[0];
    const float* w1   = (const float*)d_in[1];
    const float* b1   = (const float*)d_in[2];
    const float* w2   = (const float*)d_in[3];
    const float* b2   = (const float*)d_in[4];
    const float* w3   = (const float*)d_in[5];
    const float* b3   = (const float*)d_in[6];
    const float* w4   = (const float*)d_in[7];
    const int*   gidx = (const int*)d_in[8];
    float* out = (float*)d_out;
    bf16_t* wf = (bf16_t*)d_ws;                 // needs 3*65536 bf16 = 384 KB

    int nbat = in_sizes[0] / (64 * 256);        // 4096
    const size_t ws_needed = (size_t)3 * 65536 * sizeof(bf16_t);

    if (ws_size >= ws_needed) {
        prep_weights<<<768, 256, 0, stream>>>(w1, w2, w3, wf);
        policy_main<true><<<nbat, 256, 0, stream>>>(
            x, wf, w1, w2, w3, b1, b2, b3, w4, gidx, out);
    } else {
        policy_main<false><<<nbat, 256, 0, stream>>>(
            x, wf, w1, w2, w3, b1, b2, b3, w4, gidx, out);
    }
}